// Round 3
// baseline (633.419 us; speedup 1.0000x reference)
//
#include <hip/hip_runtime.h>
#include <hip/hip_bf16.h>

typedef unsigned short u16;
typedef __bf16 bf16x8 __attribute__((ext_vector_type(8)));
typedef float  f32x4  __attribute__((ext_vector_type(4)));

__device__ __forceinline__ unsigned pk2(float a, float b) {
    __hip_bfloat162 h = __float22bfloat162_rn(make_float2(a, b));
    unsigned u; __builtin_memcpy(&u, &h, 4);
    return u;   // low 16 = bf16(a), high 16 = bf16(b)
}
__device__ __forceinline__ u16 f2b1(float f) { return (u16)(pk2(f, f) & 0xFFFFu); }

#define MFMA __builtin_amdgcn_mfma_f32_16x16x32_bf16

// ---------------------------------------------------------------------------
// prep: ppK[r][j] = (pos_table[r].W_pos_w[j,128:256] + W_pos_b[j]) * 2*log2(e)
//       wb1/wb2: bf16 weights repacked into per-(n,kk) contiguous 1KB tiles:
//       element (row, col) -> [ (row>>4)*4 + (col>>5) ][ row&15 ][ col&31 ]
//       so a wave's 64 B-frag lanes (c,g) read one contiguous 1KB burst.
// ---------------------------------------------------------------------------
__global__ __launch_bounds__(128) void prep_kernel(
    const float* __restrict__ pos_table, const float* __restrict__ Wpw,
    const float* __restrict__ Wpb, const float* __restrict__ W2,
    float* __restrict__ ppK, u16* __restrict__ wb1, u16* __restrict__ wb2)
{
    const int b = blockIdx.x, t = threadIdx.x;
    if (b < 65) {
        const float4* pr = (const float4*)(pos_table + b * 128);
        const float4* wr = (const float4*)(Wpw + t * 256 + 128);
        float acc = Wpb[t];
        #pragma unroll
        for (int k = 0; k < 32; ++k) {
            const float4 p = pr[k], wv = wr[k];
            acc += p.x * wv.x + p.y * wv.y + p.z * wv.z + p.w * wv.w;
        }
        ppK[b * 128 + t] = acc * 2.885390081777927f;   // pre-scaled for exp2
    } else {
        const int j = b - 65;                          // output row 0..127
        // swizzled tile offset for (row j, col t)
        const int off = (((j >> 4) * 4 + (t >> 5)) * 16 + (j & 15)) * 32 + (t & 31);
        wb1[off] = f2b1(Wpw[j * 256 + t]);
        wb2[off] = f2b1(W2[j * 128 + t]);
    }
}

// ---------------------------------------------------------------------------
// fused v3: PERSISTENT blocks. grid = 512 (exactly 2 blocks/CU), each block
// loops over npairs/512 session-pairs with a register prefetch pipeline:
//   pf regs hold pair i+1's hidden (64KB/block) while pair i computes.
// Rationale (R0-R2 post-mortems): fused time was invariant (210-217us) under
// occupancy 22/43/31% with all pipes <25%. Per-CU HBM demand was 4.9 GB/s of
// a 24.6 GB/s fair share -> HBM duty-cycle ~20%: each block streams 64KB once,
// then computes ~25us with HBM idle. Persistent+prefetch makes the stream
// continuous and amortizes per-block overhead 8x.
// Prefetch is issued AFTER the post-convert barrier so the barrier's
// vmcnt(0) drain doesn't stall on fresh loads; it is consumed one full
// compute phase (~2-5us >> 900cy HBM latency) later.
// ---------------------------------------------------------------------------
__global__ __launch_bounds__(256, 2) void fused_kernel(
    const float* __restrict__ hidden, const int* __restrict__ rpos,
    const float* __restrict__ W1, const float* __restrict__ W1b,
    const float* __restrict__ W2b, const float* __restrict__ qw,
    const float* __restrict__ qb, const float* __restrict__ ppK,
    const u16* __restrict__ wb1g, const u16* __restrict__ wb2g,
    float* __restrict__ out, const int npairs)
{
    // 128 rows x 136 bf16 (pad +8: 272B row stride, bank-spread)
    __shared__ __align__(16) u16 hbf[128 * 136];    // 34816 B (hidden -> ph)
    __shared__ float meanv[256];                    // [2][128] fp32 sums
    __shared__ float g1s[256];                      // [2][128]
    __shared__ float qws[128];
    __shared__ float alphas[128];                   // total 37888 B

    const int tid = threadIdx.x;
    const int w = tid >> 6;                 // wave 0..3, rows 32w..32w+31
    const int l = tid & 63;
    const int c = l & 15;                   // MFMA A-row / B-row / D-col
    const int g = l >> 4;                   // quad
    const int R = 32 * w;

    if (tid < 128) qws[tid] = qw[tid];      // block-invariant; B0 orders it

    // ---- prime the pipeline: load first pair into pf regs
    int pair = blockIdx.x;
    float4 pf[16];                          // 64 VGPR, statically indexed
    {
        const float4* hp = (const float4*)(hidden + (size_t)pair * 16384);
        #pragma unroll
        for (int i = 0; i < 16; ++i) pf[i] = hp[tid + i * 256];
    }

    for (; pair < npairs; pair += gridDim.x) {
        const float* hsrc = hidden + (size_t)pair * 16384;

        // ---- B0: protects hbf/alphas/meanv reuse across iterations
        meanv[tid] = 0.f;
        __syncthreads();

        // ---- convert pf -> bf16 LDS; fp32 column sums.
        // Thread's 16 chunks hit column group (4*tid)&127; rows (tid>>5)+8i.
        // Lanes l, l^32 share the column group -> shfl fold, half the atomics.
        {
            float4 ms0 = {0.f, 0.f, 0.f, 0.f}, ms1 = {0.f, 0.f, 0.f, 0.f};
            #pragma unroll
            for (int i = 0; i < 16; ++i) {
                const int i4 = tid + i * 256;
                const float4 v = pf[i];
                const int e = i4 * 4, row = e >> 7, col = e & 127;
                uint2 st; st.x = pk2(v.x, v.y); st.y = pk2(v.z, v.w);
                *(uint2*)&hbf[row * 136 + col] = st;
                if (i < 8) { ms0.x += v.x; ms0.y += v.y; ms0.z += v.z; ms0.w += v.w; }
                else       { ms1.x += v.x; ms1.y += v.y; ms1.z += v.z; ms1.w += v.w; }
            }
            ms0.x += __shfl_xor(ms0.x, 32, 64); ms0.y += __shfl_xor(ms0.y, 32, 64);
            ms0.z += __shfl_xor(ms0.z, 32, 64); ms0.w += __shfl_xor(ms0.w, 32, 64);
            ms1.x += __shfl_xor(ms1.x, 32, 64); ms1.y += __shfl_xor(ms1.y, 32, 64);
            ms1.z += __shfl_xor(ms1.z, 32, 64); ms1.w += __shfl_xor(ms1.w, 32, 64);
            if ((l & 32) == 0) {
                const int mc = (tid * 4) & 127;
                atomicAdd(&meanv[mc],           ms0.x); atomicAdd(&meanv[mc + 1],       ms0.y);
                atomicAdd(&meanv[mc + 2],       ms0.z); atomicAdd(&meanv[mc + 3],       ms0.w);
                atomicAdd(&meanv[128 + mc],     ms1.x); atomicAdd(&meanv[128 + mc + 1], ms1.y);
                atomicAdd(&meanv[128 + mc + 2], ms1.z); atomicAdd(&meanv[128 + mc + 3], ms1.w);
            }
        }
        __syncthreads();    // B1: hbf + meanv complete

        // ---- issue prefetch of next pair; flies under g1+GEMM1+GEMM2
        {
            const int nxt = pair + gridDim.x;
            if (nxt < npairs) {
                const float4* hp = (const float4*)(hidden + (size_t)nxt * 16384);
                #pragma unroll
                for (int i = 0; i < 16; ++i) pf[i] = hp[tid + i * 256];
            }
        }

        // ---- g1[s][col] = mean[s].W1[col]/64 + W1_b + W2_b  (2 acc chains)
        {
            const int col = tid & 127, s = tid >> 7;
            const float4* wr = (const float4*)(W1 + col * 128);
            const float4* mv = (const float4*)(meanv + s * 128);
            float a0 = 0.f, a1 = 0.f;
            #pragma unroll 8
            for (int k4 = 0; k4 < 32; k4 += 2) {
                const float4 w0 = wr[k4], m0 = mv[k4];
                const float4 w1v = wr[k4 + 1], m1 = mv[k4 + 1];
                a0 += m0.x * w0.x + m0.y * w0.y + m0.z * w0.z + m0.w * w0.w;
                a1 += m1.x * w1v.x + m1.y * w1v.y + m1.z * w1v.z + m1.w * w1v.w;
            }
            g1s[tid] = W1b[col] + W2b[col] + (a0 + a1) * (1.f / 64.f);
        }

        // ---- GEMM1 A-frags (hidden, own wave's rows only)
        bf16x8 af[2][4];
        #pragma unroll
        for (int m = 0; m < 2; ++m)
            #pragma unroll
            for (int kk = 0; kk < 4; ++kk)
                af[m][kk] = *(const bf16x8*)&hbf[(R + 16 * m + c) * 136 + kk * 32 + g * 8];

        int pko[2][4];              // ppK element offsets per (m,r); rpos direct
        #pragma unroll
        for (int m = 0; m < 2; ++m)
            #pragma unroll
            for (int r = 0; r < 4; ++r)
                pko[m][r] = rpos[pair * 128 + R + 16 * m + 4 * g + r] * 128 + c;

        // ---- GEMM1: ph = tanh(hidden @ Wpa^T + pp), fused act, in-place
        {
            const u16* wb1p = wb1g + c * 32 + g * 8;
            const float K2 = 2.885390081777927f;        // 2*log2(e)
            #pragma unroll
            for (int n = 0; n < 8; ++n) {
                float ppv[2][4];
                #pragma unroll
                for (int m = 0; m < 2; ++m)
                    #pragma unroll
                    for (int r = 0; r < 4; ++r)
                        ppv[m][r] = ppK[pko[m][r] + 16 * n];
                bf16x8 b0 = *(const bf16x8*)(wb1p + n * 2048);
                bf16x8 b1 = *(const bf16x8*)(wb1p + n * 2048 + 512);
                bf16x8 b2 = *(const bf16x8*)(wb1p + n * 2048 + 1024);
                bf16x8 b3 = *(const bf16x8*)(wb1p + n * 2048 + 1536);
                f32x4 acc[2] = {};
                acc[0] = MFMA(af[0][0], b0, acc[0], 0, 0, 0);
                acc[1] = MFMA(af[1][0], b0, acc[1], 0, 0, 0);
                acc[0] = MFMA(af[0][1], b1, acc[0], 0, 0, 0);
                acc[1] = MFMA(af[1][1], b1, acc[1], 0, 0, 0);
                acc[0] = MFMA(af[0][2], b2, acc[0], 0, 0, 0);
                acc[1] = MFMA(af[1][2], b2, acc[1], 0, 0, 0);
                acc[0] = MFMA(af[0][3], b3, acc[0], 0, 0, 0);
                acc[1] = MFMA(af[1][3], b3, acc[1], 0, 0, 0);
                #pragma unroll
                for (int m = 0; m < 2; ++m)
                    #pragma unroll
                    for (int r = 0; r < 4; ++r) {
                        const float arg = fmaf(acc[m][r], K2, ppv[m][r]);
                        const float e2 = __builtin_amdgcn_exp2f(arg);
                        const float rc = __builtin_amdgcn_rcpf(e2 + 1.f);
                        hbf[(R + 16 * m + 4 * g + r) * 136 + 16 * n + c] =
                            f2b1(fmaf(-2.f, rc, 1.f));          // tanh
                    }
            }
        }

        // ---- GEMM2 A-frags (ph, own rows; same-wave ds order is safe)
        bf16x8 af2[2][4];
        #pragma unroll
        for (int m = 0; m < 2; ++m)
            #pragma unroll
            for (int kk = 0; kk < 4; ++kk)
                af2[m][kk] = *(const bf16x8*)&hbf[(R + 16 * m + c) * 136 + kk * 32 + g * 8];

        __syncthreads();    // B1.5: g1s (cross-wave) visible

        // ---- GEMM2: gate = sigmoid(g1 + ph @ W2^T); alpha = gate.qw + qb
        {
            const u16* wb2p = wb2g + c * 32 + g * 8;
            const float K1 = 1.4426950408889634f;       // log2(e)
            const int sw = w >> 1;                      // wave's session
            float prt[2][4] = {};
            #pragma unroll
            for (int n = 0; n < 8; ++n) {
                bf16x8 b0 = *(const bf16x8*)(wb2p + n * 2048);
                bf16x8 b1 = *(const bf16x8*)(wb2p + n * 2048 + 512);
                bf16x8 b2 = *(const bf16x8*)(wb2p + n * 2048 + 1024);
                bf16x8 b3 = *(const bf16x8*)(wb2p + n * 2048 + 1536);
                f32x4 acc[2] = {};
                acc[0] = MFMA(af2[0][0], b0, acc[0], 0, 0, 0);
                acc[1] = MFMA(af2[1][0], b0, acc[1], 0, 0, 0);
                acc[0] = MFMA(af2[0][1], b1, acc[0], 0, 0, 0);
                acc[1] = MFMA(af2[1][1], b1, acc[1], 0, 0, 0);
                acc[0] = MFMA(af2[0][2], b2, acc[0], 0, 0, 0);
                acc[1] = MFMA(af2[1][2], b2, acc[1], 0, 0, 0);
                acc[0] = MFMA(af2[0][3], b3, acc[0], 0, 0, 0);
                acc[1] = MFMA(af2[1][3], b3, acc[1], 0, 0, 0);
                const float gv = -K1 * g1s[sw * 128 + 16 * n + c];
                const float qv = qws[16 * n + c];
                #pragma unroll
                for (int m = 0; m < 2; ++m)
                    #pragma unroll
                    for (int r = 0; r < 4; ++r) {
                        const float arg = fmaf(acc[m][r], -K1, gv);
                        const float e2 = __builtin_amdgcn_exp2f(arg);
                        const float rc = __builtin_amdgcn_rcpf(e2 + 1.f);   // sigmoid
                        prt[m][r] = fmaf(rc, qv, prt[m][r]);
                    }
            }
            #pragma unroll
            for (int msk = 1; msk <= 8; msk <<= 1)
                #pragma unroll
                for (int m = 0; m < 2; ++m)
                    #pragma unroll
                    for (int r = 0; r < 4; ++r)
                        prt[m][r] += __shfl_xor(prt[m][r], msk, 64);
            if (c == 0) {
                const float qbv = qb[0];
                #pragma unroll
                for (int m = 0; m < 2; ++m)
                    #pragma unroll
                    for (int r = 0; r < 4; ++r)
                        alphas[R + 16 * m + 4 * g + r] = prt[m][r] + qbv;
            }
        }
        __syncthreads();    // B2: alphas visible

        // ---- out[s] = sum_t alpha_t * hidden[t]  (fp32, L2-hot re-read;
        //      16 loads in flight, 8 independent FMA chains)
        {
            const int h = tid & 127, p = tid >> 7;
            const float* hs = hsrc + p * (64 * 128) + h;
            float a8[8];
            #pragma unroll
            for (int j = 0; j < 8; ++j) a8[j] = 0.f;
            #pragma unroll
            for (int t0 = 0; t0 < 4; ++t0) {
                float v[16], al[16];
                #pragma unroll
                for (int j = 0; j < 16; ++j) {
                    v[j]  = hs[(t0 * 16 + j) * 128];
                    al[j] = alphas[64 * p + t0 * 16 + j];
                }
                #pragma unroll
                for (int j = 0; j < 16; ++j) a8[j & 7] = fmaf(al[j], v[j], a8[j & 7]);
            }
            const float accf = ((a8[0] + a8[1]) + (a8[2] + a8[3]))
                             + ((a8[4] + a8[5]) + (a8[6] + a8[7]));
            out[(size_t)pair * 256 + tid] = accf;
        }
        // no trailing barrier: next iteration's B0 orders hbf/meanv reuse
    }
}

// ---------------------------------------------------------------------------
extern "C" void kernel_launch(void* const* d_in, const int* in_sizes, int n_in,
                              void* d_out, int out_size, void* d_ws, size_t ws_size,
                              hipStream_t stream)
{
    const float* hidden    = (const float*)d_in[0];
    const float* pos_table = (const float*)d_in[1];
    const float* Wpw       = (const float*)d_in[2];
    const float* Wpb       = (const float*)d_in[3];
    const float* W1w       = (const float*)d_in[4];
    const float* W1b       = (const float*)d_in[5];
    const float* W2w       = (const float*)d_in[6];
    const float* W2b       = (const float*)d_in[7];
    const float* qw        = (const float*)d_in[8];
    const float* qb        = (const float*)d_in[9];
    const int*   rpos      = (const int*)d_in[11];
    float* out = (float*)d_out;

    const int B = in_sizes[10];              // sessions (8192)
    const int npairs = B / 2;                // 4096
    const int grid = npairs < 512 ? npairs : 512;   // 2 blocks/CU, persistent

    // workspace layout (98816 B total)
    char* wsb = (char*)d_ws;
    float* ppK = (float*)wsb;                        // 65*128*4 = 33280
    u16* wb1   = (u16*)(wsb + 33280);                // 32768
    u16* wb2   = (u16*)(wsb + 33280 + 32768);        // 32768

    prep_kernel<<<193, 128, 0, stream>>>(pos_table, Wpw, Wpb, W2w,
                                         ppK, wb1, wb2);
    fused_kernel<<<grid, 256, 0, stream>>>(hidden, rpos, W1w, W1b, W2b, qw, qb,
                                           ppK, wb1, wb2, out, npairs);
}

// Round 4
// 437.901 us; speedup vs baseline: 1.4465x; 1.4465x over previous
//
#include <hip/hip_runtime.h>
#include <hip/hip_bf16.h>

typedef unsigned short u16;
typedef __bf16 bf16x8 __attribute__((ext_vector_type(8)));
typedef float  f32x4  __attribute__((ext_vector_type(4)));

__device__ __forceinline__ unsigned pk2(float a, float b) {
    __hip_bfloat162 h = __float22bfloat162_rn(make_float2(a, b));
    unsigned u; __builtin_memcpy(&u, &h, 4);
    return u;   // low 16 = bf16(a), high 16 = bf16(b)
}
__device__ __forceinline__ u16 f2b1(float f) { return (u16)(pk2(f, f) & 0xFFFFu); }

__device__ __forceinline__ bf16x8 pack8(const float4 a, const float4 b) {
    unsigned u0 = pk2(a.x, a.y), u1 = pk2(a.z, a.w);
    unsigned u2 = pk2(b.x, b.y), u3 = pk2(b.z, b.w);
    unsigned arr[4] = {u0, u1, u2, u3};
    bf16x8 r; __builtin_memcpy(&r, arr, 16);
    return r;
}

#define MFMA __builtin_amdgcn_mfma_f32_16x16x32_bf16

// ---------------------------------------------------------------------------
// prep: ppK[r][j] = (pos_table[r].W_pos_w[j,128:256] + W_pos_b[j]) * 2*log2(e)
//       wb1/wb2/wb3: bf16 weights repacked into per-(n,kk) contiguous 1KB
//       tiles, element (row j, col t) ->
//         [ (j>>4)*4 + (t>>5) ][ j&15 ][ t&31 ]
//       (wb1 = Wpw[:, :128], wb2 = W2, wb3 = W1 for the mean-GEMM).
//       bsum[t] = W1_b[t] + W2_b[t].
// ---------------------------------------------------------------------------
__global__ __launch_bounds__(128) void prep_kernel(
    const float* __restrict__ pos_table, const float* __restrict__ Wpw,
    const float* __restrict__ Wpb, const float* __restrict__ W2,
    const float* __restrict__ W1, const float* __restrict__ W1b,
    const float* __restrict__ W2b,
    float* __restrict__ ppK, u16* __restrict__ wb1, u16* __restrict__ wb2,
    u16* __restrict__ wb3, float* __restrict__ bsum)
{
    const int b = blockIdx.x, t = threadIdx.x;
    if (b < 65) {
        const float4* pr = (const float4*)(pos_table + b * 128);
        const float4* wr = (const float4*)(Wpw + t * 256 + 128);
        float acc = Wpb[t];
        #pragma unroll
        for (int k = 0; k < 32; ++k) {
            const float4 p = pr[k], wv = wr[k];
            acc += p.x * wv.x + p.y * wv.y + p.z * wv.z + p.w * wv.w;
        }
        ppK[b * 128 + t] = acc * 2.885390081777927f;   // pre-scaled for exp2
    } else {
        const int j = b - 65;                          // output row 0..127
        const int off = (((j >> 4) * 4 + (t >> 5)) * 16 + (j & 15)) * 32 + (t & 31);
        wb1[off] = f2b1(Wpw[j * 256 + t]);
        wb2[off] = f2b1(W2[j * 128 + t]);
        wb3[off] = f2b1(W1[j * 128 + t]);
        if (j == 0) bsum[t] = W1b[t] + W2b[t];
    }
}

// ---------------------------------------------------------------------------
// fused v4: ONE WAVE = ONE SESSION. Zero __syncthreads.
// Rationale (R0-R3): time invariant ~210us under occupancy 22-43%, LDS-
// conflict 5x, VGPR 64-92 -> the block-wide barrier-phased structure itself
// is the serializer (VALUBusy 23% = 77% of cycles NO wave can issue).
// Each wave: direct global A-frag loads (no staging LDS), mean via 4
// shfl_xor steps (lane already holds its fragment's columns), mean@W1 done
// ON THE MFMA (row-uniform mean A-frag x wb3 tile -> D feeds GEMM2's C-in),
// ph relayout through a PRIVATE per-wave LDS slice (wave-local ds order,
// no barrier). 4 m-tiles/wave = 2x MFMA per B-frag load. 8 independent
// waves/CU -> compiler can pipeline each wave end-to-end.
// LDS 70656 B -> 2 blocks/CU.
// ---------------------------------------------------------------------------
__global__ __launch_bounds__(256, 2) void fused_kernel(
    const float* __restrict__ hidden, const int* __restrict__ rpos,
    const float* __restrict__ qw, const float* __restrict__ qb,
    const float* __restrict__ ppK, const u16* __restrict__ wb1g,
    const u16* __restrict__ wb2g, const u16* __restrict__ wb3g,
    const float* __restrict__ bsum, float* __restrict__ out)
{
    __shared__ __align__(16) u16 phs[4 * 64 * 136];  // per-wave 64x136 ph slices
    __shared__ __align__(16) float alphas[4 * 64];   // per-wave alpha strips

    const int tid = threadIdx.x;
    const int w = tid >> 6;                 // wave -> session within block
    const int l = tid & 63;
    const int c = l & 15;                   // MFMA A-row / D-col
    const int g = l >> 4;                   // quad
    const int s = blockIdx.x * 4 + w;       // session id
    const float* hs = hidden + (size_t)s * (64 * 128);
    u16* ph = phs + w * (64 * 136);
    float* alw = alphas + w * 64;

    // ---- load A-frags direct from global + per-lane column partial sums.
    // Lane (c,g) reads rows {16m+c}, cols {32kk+8g .. +7}: the full session
    // tile across the wave. cs[kk][j] accumulates its 4 rows per column.
    bf16x8 af[4][4];
    float cs[4][8];
    #pragma unroll
    for (int kk = 0; kk < 4; ++kk)
        #pragma unroll
        for (int j = 0; j < 8; ++j) cs[kk][j] = 0.f;
    #pragma unroll
    for (int m = 0; m < 4; ++m)
        #pragma unroll
        for (int kk = 0; kk < 4; ++kk) {
            const float4* p = (const float4*)(hs + (16 * m + c) * 128 + 32 * kk + 8 * g);
            const float4 v0 = p[0], v1 = p[1];
            cs[kk][0] += v0.x; cs[kk][1] += v0.y; cs[kk][2] += v0.z; cs[kk][3] += v0.w;
            cs[kk][4] += v1.x; cs[kk][5] += v1.y; cs[kk][6] += v1.z; cs[kk][7] += v1.w;
            af[m][kk] = pack8(v0, v1);
        }

    // ---- column sums across the 16 c-lanes (masks<16 stay in the g-group);
    // then mean = cs/64 packed as a row-uniform A-frag (exactly the columns
    // this lane supplies for the mean@W1 MFMA).
    #pragma unroll
    for (int msk = 1; msk <= 8; msk <<= 1)
        #pragma unroll
        for (int kk = 0; kk < 4; ++kk)
            #pragma unroll
            for (int j = 0; j < 8; ++j)
                cs[kk][j] += __shfl_xor(cs[kk][j], msk, 64);
    bf16x8 afm[4];
    #pragma unroll
    for (int kk = 0; kk < 4; ++kk) {
        float4 a, b;
        a.x = cs[kk][0] * (1.f / 64.f); a.y = cs[kk][1] * (1.f / 64.f);
        a.z = cs[kk][2] * (1.f / 64.f); a.w = cs[kk][3] * (1.f / 64.f);
        b.x = cs[kk][4] * (1.f / 64.f); b.y = cs[kk][5] * (1.f / 64.f);
        b.z = cs[kk][6] * (1.f / 64.f); b.w = cs[kk][7] * (1.f / 64.f);
        afm[kk] = pack8(a, b);
    }

    // ---- ppK row offsets for this lane's 16 output rows (int4 loads)
    int pko[4][4];
    {
        const int* rp = rpos + s * 64;
        #pragma unroll
        for (int m = 0; m < 4; ++m) {
            const int4 rv = *(const int4*)(rp + 16 * m + 4 * g);
            pko[m][0] = rv.x * 128 + c; pko[m][1] = rv.y * 128 + c;
            pko[m][2] = rv.z * 128 + c; pko[m][3] = rv.w * 128 + c;
        }
    }

    // ---- GEMM1: ph = tanh(hidden @ Wpa^T + pp); D written to wave's LDS
    {
        const u16* wb1p = wb1g + c * 32 + g * 8;
        const float K2 = 2.885390081777927f;        // 2*log2(e)
        #pragma unroll
        for (int n = 0; n < 8; ++n) {
            float ppv[4][4];
            #pragma unroll
            for (int m = 0; m < 4; ++m)
                #pragma unroll
                for (int r = 0; r < 4; ++r)
                    ppv[m][r] = ppK[pko[m][r] + 16 * n];
            const bf16x8 b0 = *(const bf16x8*)(wb1p + n * 2048);
            const bf16x8 b1 = *(const bf16x8*)(wb1p + n * 2048 + 512);
            const bf16x8 b2 = *(const bf16x8*)(wb1p + n * 2048 + 1024);
            const bf16x8 b3 = *(const bf16x8*)(wb1p + n * 2048 + 1536);
            f32x4 acc[4] = {};
            #pragma unroll
            for (int m = 0; m < 4; ++m) {
                acc[m] = MFMA(af[m][0], b0, acc[m], 0, 0, 0);
                acc[m] = MFMA(af[m][1], b1, acc[m], 0, 0, 0);
                acc[m] = MFMA(af[m][2], b2, acc[m], 0, 0, 0);
                acc[m] = MFMA(af[m][3], b3, acc[m], 0, 0, 0);
            }
            #pragma unroll
            for (int m = 0; m < 4; ++m)
                #pragma unroll
                for (int r = 0; r < 4; ++r) {
                    const float arg = fmaf(acc[m][r], K2, ppv[m][r]);
                    const float e2 = __builtin_amdgcn_exp2f(arg);
                    const float rc = __builtin_amdgcn_rcpf(e2 + 1.f);
                    ph[(16 * m + 4 * g + r) * 136 + 16 * n + c] =
                        f2b1(fmaf(-2.f, rc, 1.f));          // tanh
                }
        }
    }

    // ---- GEMM2 A-frags from wave-private ph (same-wave ds order is safe)
    bf16x8 af2[4][4];
    #pragma unroll
    for (int m = 0; m < 4; ++m)
        #pragma unroll
        for (int kk = 0; kk < 4; ++kk)
            af2[m][kk] = *(const bf16x8*)&ph[(16 * m + c) * 136 + kk * 32 + g * 8];

    // ---- GEMM2: pre = mean@W1 (row-uniform MFMA, C-in) + ph@W2; fused
    //      sigmoid; alpha partials accumulated per lane.
    {
        const u16* wb2p = wb2g + c * 32 + g * 8;
        const u16* wb3p = wb3g + c * 32 + g * 8;
        const float K1 = 1.4426950408889634f;       // log2(e)
        float prt[4][4] = {};
        #pragma unroll
        for (int n = 0; n < 8; ++n) {
            const bf16x8 m0 = *(const bf16x8*)(wb3p + n * 2048);
            const bf16x8 m1 = *(const bf16x8*)(wb3p + n * 2048 + 512);
            const bf16x8 m2 = *(const bf16x8*)(wb3p + n * 2048 + 1024);
            const bf16x8 m3 = *(const bf16x8*)(wb3p + n * 2048 + 1536);
            f32x4 accM = {};
            accM = MFMA(afm[0], m0, accM, 0, 0, 0);
            accM = MFMA(afm[1], m1, accM, 0, 0, 0);
            accM = MFMA(afm[2], m2, accM, 0, 0, 0);
            accM = MFMA(afm[3], m3, accM, 0, 0, 0);
            const bf16x8 b0 = *(const bf16x8*)(wb2p + n * 2048);
            const bf16x8 b1 = *(const bf16x8*)(wb2p + n * 2048 + 512);
            const bf16x8 b2 = *(const bf16x8*)(wb2p + n * 2048 + 1024);
            const bf16x8 b3 = *(const bf16x8*)(wb2p + n * 2048 + 1536);
            const float gvn = -K1 * bsum[16 * n + c];
            const float qv  = qw[16 * n + c];
            #pragma unroll
            for (int m = 0; m < 4; ++m) {
                f32x4 a = accM;                      // mean@W1 as C-input
                a = MFMA(af2[m][0], b0, a, 0, 0, 0);
                a = MFMA(af2[m][1], b1, a, 0, 0, 0);
                a = MFMA(af2[m][2], b2, a, 0, 0, 0);
                a = MFMA(af2[m][3], b3, a, 0, 0, 0);
                #pragma unroll
                for (int r = 0; r < 4; ++r) {
                    const float arg = fmaf(a[r], -K1, gvn);
                    const float e2 = __builtin_amdgcn_exp2f(arg);
                    const float rc = __builtin_amdgcn_rcpf(e2 + 1.f);   // sigmoid
                    prt[m][r] = fmaf(rc, qv, prt[m][r]);
                }
            }
        }
        // reduce alpha over the 16 c-lanes (cols); masks<16 stay in-group
        #pragma unroll
        for (int msk = 1; msk <= 8; msk <<= 1)
            #pragma unroll
            for (int m = 0; m < 4; ++m)
                #pragma unroll
                for (int r = 0; r < 4; ++r)
                    prt[m][r] += __shfl_xor(prt[m][r], msk, 64);
        if (c == 0) {
            const float qbv = qb[0];
            #pragma unroll
            for (int m = 0; m < 4; ++m)
                #pragma unroll
                for (int r = 0; r < 4; ++r)
                    alw[16 * m + 4 * g + r] = prt[m][r] + qbv;
        }
    }

    // ---- out[s][h] = sum_t alpha_t * hidden[t][h]; lane handles h=l, 64+l.
    //      alphas via float4 LDS broadcast; 8 independent FMA chains.
    {
        float a0[4] = {0.f, 0.f, 0.f, 0.f}, a1[4] = {0.f, 0.f, 0.f, 0.f};
        #pragma unroll
        for (int t4 = 0; t4 < 16; ++t4) {
            const float4 av = *(const float4*)&alw[t4 * 4];
            const float* hr = hs + (t4 * 4) * 128;
            a0[0] = fmaf(av.x, hr[l], a0[0]);       a1[0] = fmaf(av.x, hr[64 + l], a1[0]);
            a0[1] = fmaf(av.y, hr[128 + l], a0[1]); a1[1] = fmaf(av.y, hr[192 + l], a1[1]);
            a0[2] = fmaf(av.z, hr[256 + l], a0[2]); a1[2] = fmaf(av.z, hr[320 + l], a1[2]);
            a0[3] = fmaf(av.w, hr[384 + l], a0[3]); a1[3] = fmaf(av.w, hr[448 + l], a1[3]);
        }
        out[(size_t)s * 128 + l]      = (a0[0] + a0[1]) + (a0[2] + a0[3]);
        out[(size_t)s * 128 + 64 + l] = (a1[0] + a1[1]) + (a1[2] + a1[3]);
    }
}

// ---------------------------------------------------------------------------
extern "C" void kernel_launch(void* const* d_in, const int* in_sizes, int n_in,
                              void* d_out, int out_size, void* d_ws, size_t ws_size,
                              hipStream_t stream)
{
    const float* hidden    = (const float*)d_in[0];
    const float* pos_table = (const float*)d_in[1];
    const float* Wpw       = (const float*)d_in[2];
    const float* Wpb       = (const float*)d_in[3];
    const float* W1w       = (const float*)d_in[4];
    const float* W1b       = (const float*)d_in[5];
    const float* W2w       = (const float*)d_in[6];
    const float* W2b       = (const float*)d_in[7];
    const float* qw        = (const float*)d_in[8];
    const float* qb        = (const float*)d_in[9];
    const int*   rpos      = (const int*)d_in[11];
    float* out = (float*)d_out;

    const int B = in_sizes[10];              // sessions (8192)

    // workspace layout (132096 B total)
    char* wsb = (char*)d_ws;
    float* ppK  = (float*)wsb;                           // 65*128*4 = 33280
    u16*   wb1  = (u16*)(wsb + 33280);                   // 32768
    u16*   wb2  = (u16*)(wsb + 33280 + 32768);           // 32768
    u16*   wb3  = (u16*)(wsb + 33280 + 2 * 32768);       // 32768
    float* bsum = (float*)(wsb + 33280 + 3 * 32768);     // 512

    prep_kernel<<<193, 128, 0, stream>>>(pos_table, Wpw, Wpb, W2w, W1w, W1b, W2b,
                                         ppK, wb1, wb2, wb3, bsum);
    fused_kernel<<<B / 4, 256, 0, stream>>>(hidden, rpos, qw, qb,
                                            ppK, wb1, wb2, wb3, bsum, out);
}